// Round 1
// baseline (382.470 us; speedup 1.0000x reference)
//
#include <hip/hip_runtime.h>
#include <hip/hip_bf16.h>

typedef __attribute__((ext_vector_type(8))) short short8;
typedef __attribute__((ext_vector_type(4))) float f32x4;

#define LN_EPS 1e-5f

__device__ __forceinline__ ushort f32_to_bf16(float f) {
  union { float f; unsigned u; } v; v.f = f;
  unsigned u = v.u;
  u += 0x7FFFu + ((u >> 16) & 1u);   // RNE
  return (ushort)(u >> 16);
}
__device__ __forceinline__ float bf16_to_f32(ushort h) {
  union { unsigned u; float f; } v; v.u = ((unsigned)h) << 16; return v.f;
}
__device__ __forceinline__ float sigmoid_f(float x) {
  return 1.0f / (1.0f + __expf(-x));
}
__device__ __forceinline__ float tanh_f(float x) {
  return 2.0f / (1.0f + __expf(-2.0f * x)) - 1.0f;
}

// ---------------- cast f32 -> bf16, vectorized (float4 in, ushort4 out) ----
__global__ __launch_bounds__(256) void cast_f32_bf16(const float* __restrict__ in,
                                                     ushort* __restrict__ out, int n4) {
  int i = blockIdx.x * 256 + threadIdx.x;
  int stride = gridDim.x * 256;
  for (; i < n4; i += stride) {
    float4 v = ((const float4*)in)[i];
    ushort4 o;
    o.x = f32_to_bf16(v.x); o.y = f32_to_bf16(v.y);
    o.z = f32_to_bf16(v.z); o.w = f32_to_bf16(v.w);
    ((ushort4*)out)[i] = o;
  }
}

// ---------------- NT bf16 GEMM: C[m][n] = sum_k A[m][k] * B[n][k] ----------
// 128x128 tile, BK=32, 4 waves (2x2), each wave 64x64 = 4x4 frags of 16x16x32.
// Writes C as bf16.
__global__ __launch_bounds__(256) void gemm_bt(const ushort* __restrict__ A,
                                               const ushort* __restrict__ B,
                                               ushort* __restrict__ C,
                                               int M, int N, int K) {
  __shared__ alignas(16) ushort As[128][40];  // +8 pad: <=2-way bank alias (free)
  __shared__ alignas(16) ushort Bs[128][40];
  const int tid = threadIdx.x;
  const int lane = tid & 63;
  const int wave = tid >> 6;
  const int wm = wave >> 1, wn = wave & 1;
  const int bn = blockIdx.x, bm = blockIdx.y;

  f32x4 acc[4][4];
#pragma unroll
  for (int i = 0; i < 4; i++)
#pragma unroll
    for (int j = 0; j < 4; j++) acc[i][j] = (f32x4){0.f, 0.f, 0.f, 0.f};

  const int srow = tid >> 2;          // 0..63
  const int scol = (tid & 3) << 3;    // 0,8,16,24
  const ushort* Ag = A + (size_t)(bm * 128 + srow) * K + scol;
  const ushort* Bg = B + (size_t)(bn * 128 + srow) * K + scol;
  const int frow = lane & 15;
  const int fcol = (lane >> 4) << 3;

  for (int k0 = 0; k0 < K; k0 += 32) {
    short8 a0 = *(const short8*)(Ag);
    short8 a1 = *(const short8*)(Ag + (size_t)64 * K);
    short8 b0 = *(const short8*)(Bg);
    short8 b1 = *(const short8*)(Bg + (size_t)64 * K);
    __syncthreads();   // all waves done reading LDS from previous step
    *(short8*)&As[srow][scol]      = a0;
    *(short8*)&As[srow + 64][scol] = a1;
    *(short8*)&Bs[srow][scol]      = b0;
    *(short8*)&Bs[srow + 64][scol] = b1;
    __syncthreads();
    Ag += 32; Bg += 32;

    short8 af[4], bfr[4];
#pragma unroll
    for (int i = 0; i < 4; i++) af[i]  = *(const short8*)&As[wm * 64 + i * 16 + frow][fcol];
#pragma unroll
    for (int j = 0; j < 4; j++) bfr[j] = *(const short8*)&Bs[wn * 64 + j * 16 + frow][fcol];
#pragma unroll
    for (int i = 0; i < 4; i++)
#pragma unroll
      for (int j = 0; j < 4; j++)
        acc[i][j] = __builtin_amdgcn_mfma_f32_16x16x32_bf16(af[i], bfr[j], acc[i][j], 0, 0, 0);
  }

  // C/D mapping (m89): col = lane&15, row = (lane>>4)*4 + reg
  const int crow0 = bm * 128 + wm * 64;
  const int ccol0 = bn * 128 + wn * 64;
#pragma unroll
  for (int i = 0; i < 4; i++)
#pragma unroll
    for (int j = 0; j < 4; j++) {
      int col = ccol0 + j * 16 + (lane & 15);
      int rb = crow0 + i * 16 + ((lane >> 4) << 2);
#pragma unroll
      for (int r = 0; r < 4; r++)
        C[(size_t)(rb + r) * N + col] = f32_to_bf16(acc[i][j][r]);
    }
}

// ---------------- fused: LN(4H) + add input + LSTM gates + LN(H) + out -----
// one block (256 threads) per row; H = 1024 assumed (gates_s sized 4096)
__global__ __launch_bounds__(256) void lstm_ln_kernel(
    const ushort* __restrict__ gates_pre,  // [B][4H] bf16
    const float* __restrict__ input,       // [B][4H]
    const float* __restrict__ cx,          // [B][H]
    const float* __restrict__ gamma_h, const float* __restrict__ beta_h,
    const float* __restrict__ gamma_c, const float* __restrict__ beta_c,
    float* __restrict__ hy, float* __restrict__ cy, int H) {
  const int FH = 4 * H;       // 4096
  const int row = blockIdx.x;
  const int t = threadIdx.x;
  const int lane = t & 63, wv = t >> 6;
  __shared__ float gates_s[4096];
  __shared__ float redA[8], redB[8];

  const ushort* gp = gates_pre + (size_t)row * FH;
  const int c0 = t * 8;         // first 8-col group
  const int c1 = 2048 + t * 8;  // second 8-col group

  float x[16];
  {
    uint4 u0 = *(const uint4*)(gp + c0);
    uint4 u1 = *(const uint4*)(gp + c1);
    const unsigned* pu0 = (const unsigned*)&u0;
    const unsigned* pu1 = (const unsigned*)&u1;
#pragma unroll
    for (int q = 0; q < 4; q++) {
      x[2 * q]     = bf16_to_f32((ushort)(pu0[q] & 0xFFFFu));
      x[2 * q + 1] = bf16_to_f32((ushort)(pu0[q] >> 16));
      x[8 + 2 * q]     = bf16_to_f32((ushort)(pu1[q] & 0xFFFFu));
      x[8 + 2 * q + 1] = bf16_to_f32((ushort)(pu1[q] >> 16));
    }
  }

  float s1 = 0.f, s2 = 0.f;
#pragma unroll
  for (int q = 0; q < 16; q++) { s1 += x[q]; s2 += x[q] * x[q]; }
  {
    float a = s1, b = s2;
#pragma unroll
    for (int off = 32; off > 0; off >>= 1) {
      a += __shfl_down(a, off, 64);
      b += __shfl_down(b, off, 64);
    }
    if (lane == 0) { redA[wv] = a; redA[4 + wv] = b; }
  }
  __syncthreads();
  const float mu  = (redA[0] + redA[1] + redA[2] + redA[3]) * (1.0f / 4096.f);
  const float m2  = (redA[4] + redA[5] + redA[6] + redA[7]) * (1.0f / 4096.f);
  const float rstd = rsqrtf(m2 - mu * mu + LN_EPS);

  const float* ip = input + (size_t)row * FH;
#pragma unroll
  for (int h = 0; h < 2; h++) {
    const int cc = (h == 0) ? c0 : c1;
    const int xo = h * 8;
    float iv[8], gv[8], bv[8];
    *(float4*)&iv[0] = *(const float4*)(ip + cc);
    *(float4*)&iv[4] = *(const float4*)(ip + cc + 4);
    *(float4*)&gv[0] = *(const float4*)(gamma_h + cc);
    *(float4*)&gv[4] = *(const float4*)(gamma_h + cc + 4);
    *(float4*)&bv[0] = *(const float4*)(beta_h + cc);
    *(float4*)&bv[4] = *(const float4*)(beta_h + cc + 4);
#pragma unroll
    for (int q = 0; q < 8; q++)
      gates_s[cc + q] = (x[xo + q] - mu) * rstd * gv[q] + bv[q] + iv[q];
  }
  __syncthreads();

  const float* cxp = cx + (size_t)row * H;
  float cell[4], og[4];
  float s3 = 0.f, s4 = 0.f;
#pragma unroll
  for (int k = 0; k < 4; k++) {
    const int j = t + 256 * k;          // strided: bank-conflict-free LDS reads
    float ig = gates_s[j];
    float fg = gates_s[H + j];
    float cg = gates_s[2 * H + j];
    float oo = gates_s[3 * H + j];
    float in_s = sigmoid_f(ig);
    float fg_s = sigmoid_f(fg);
    float cg_t = tanh_f(cg);
    og[k] = sigmoid_f(oo);
    float cl = fg_s * cxp[j] + in_s * cg_t;
    cell[k] = cl;
    s3 += cl; s4 += cl * cl;
  }
  {
    float a = s3, b = s4;
#pragma unroll
    for (int off = 32; off > 0; off >>= 1) {
      a += __shfl_down(a, off, 64);
      b += __shfl_down(b, off, 64);
    }
    if (lane == 0) { redB[wv] = a; redB[4 + wv] = b; }
  }
  __syncthreads();
  const float mu2   = (redB[0] + redB[1] + redB[2] + redB[3]) * (1.0f / 1024.f);
  const float m22   = (redB[4] + redB[5] + redB[6] + redB[7]) * (1.0f / 1024.f);
  const float rstd2 = rsqrtf(m22 - mu2 * mu2 + LN_EPS);

#pragma unroll
  for (int k = 0; k < 4; k++) {
    const int j = t + 256 * k;
    float cyv = (cell[k] - mu2) * rstd2 * gamma_c[j] + beta_c[j];
    float hyv = og[k] * tanh_f(cyv);
    cy[(size_t)row * H + j] = cyv;
    hy[(size_t)row * H + j] = hyv;
  }
}

extern "C" void kernel_launch(void* const* d_in, const int* in_sizes, int n_in,
                              void* d_out, int out_size, void* d_ws, size_t ws_size,
                              hipStream_t stream) {
  (void)n_in; (void)out_size; (void)ws_size;
  const float* input   = (const float*)d_in[0];
  const float* hx      = (const float*)d_in[1];
  const float* cx      = (const float*)d_in[2];
  const float* w       = (const float*)d_in[3];
  const float* gamma_h = (const float*)d_in[4];
  const float* beta_h  = (const float*)d_in[5];
  const float* gamma_c = (const float*)d_in[6];
  const float* beta_c  = (const float*)d_in[7];

  const int H  = in_sizes[6];       // 1024
  const int B  = in_sizes[1] / H;   // 8192
  const int FH = 4 * H;             // 4096
  const int K  = H;

  ushort* hx_bf = (ushort*)d_ws;                       // B*K bf16
  ushort* w_bf  = hx_bf + (size_t)B * K;               // FH*K bf16
  ushort* gates = w_bf + (size_t)FH * K;               // B*FH bf16

  float* hy = (float*)d_out;
  float* cy = hy + (size_t)B * H;

  cast_f32_bf16<<<2048, 256, 0, stream>>>(hx, hx_bf, (B * K) / 4);
  cast_f32_bf16<<<1024, 256, 0, stream>>>(w, w_bf, (FH * K) / 4);

  dim3 grid(FH / 128, B / 128);   // (32, 64)
  gemm_bt<<<grid, 256, 0, stream>>>(hx_bf, w_bf, gates, B, FH, K);

  lstm_ln_kernel<<<B, 256, 0, stream>>>(gates, input, cx, gamma_h, beta_h,
                                        gamma_c, beta_c, hy, cy, H);
}

// Round 2
// 365.959 us; speedup vs baseline: 1.0451x; 1.0451x over previous
//
#include <hip/hip_runtime.h>
#include <hip/hip_bf16.h>

typedef __attribute__((ext_vector_type(8))) short short8;
typedef __attribute__((ext_vector_type(4))) float f32x4;

#define LN_EPS 1e-5f

__device__ __forceinline__ ushort f32_to_bf16(float f) {
  union { float f; unsigned u; } v; v.f = f;
  unsigned u = v.u;
  u += 0x7FFFu + ((u >> 16) & 1u);   // RNE
  return (ushort)(u >> 16);
}
__device__ __forceinline__ float bf16_to_f32(ushort h) {
  union { unsigned u; float f; } v; v.u = ((unsigned)h) << 16; return v.f;
}
__device__ __forceinline__ float sigmoid_f(float x) {
  return 1.0f / (1.0f + __expf(-x));
}
__device__ __forceinline__ float tanh_f(float x) {
  return 2.0f / (1.0f + __expf(-2.0f * x)) - 1.0f;
}

// async global->LDS, 16B per lane (global_load_lds_dwordx4)
__device__ __forceinline__ void gload16(const ushort* g, ushort* l) {
  __builtin_amdgcn_global_load_lds(
      (const __attribute__((address_space(1))) unsigned int*)g,
      (__attribute__((address_space(3))) unsigned int*)l, 16, 0, 0);
}

// ---------------- fused cast f32 -> bf16 for two buffers ------------------
__global__ __launch_bounds__(256) void cast2_f32_bf16(
    const float* __restrict__ a, ushort* __restrict__ oa, int na4,
    const float* __restrict__ b, ushort* __restrict__ ob, int nb4) {
  int i = blockIdx.x * 256 + threadIdx.x;
  int stride = gridDim.x * 256;
  for (; i < na4 + nb4; i += stride) {
    const float* src = (i < na4) ? a : b;
    ushort* dst = (i < na4) ? oa : ob;
    int k = (i < na4) ? i : i - na4;
    float4 v = ((const float4*)src)[k];
    ushort4 o;
    o.x = f32_to_bf16(v.x); o.y = f32_to_bf16(v.y);
    o.z = f32_to_bf16(v.z); o.w = f32_to_bf16(v.w);
    ((ushort4*)dst)[k] = o;
  }
}

// ---------------- NT bf16 GEMM (m97 structure): C[m][n] = sum_k A[m][k]*B[n][k]
// 128x128 tile, BK=32, 4 waves (2x2), global_load_lds width-16 staging,
// linear LDS [128][32] with chunk-XOR pre-swizzled global source:
//   LDS(row, q) holds global 8-ushort chunk q ^ ((row>>1)&3)
// so fragment ds_read_b128 is only 2-way bank-aliased (free, m136).
__global__ __launch_bounds__(256) void gemm_bt(const ushort* __restrict__ A,
                                               const ushort* __restrict__ B,
                                               ushort* __restrict__ C,
                                               int M, int N, int K) {
  __shared__ alignas(16) ushort As[128 * 32];
  __shared__ alignas(16) ushort Bs[128 * 32];
  const int tid = threadIdx.x;
  const int lane = tid & 63;
  const int wave = tid >> 6;
  const int wm = wave >> 1, wn = wave & 1;
  const int bn = blockIdx.x, bm = blockIdx.y;

  f32x4 acc[4][4];
#pragma unroll
  for (int i = 0; i < 4; i++)
#pragma unroll
    for (int j = 0; j < 4; j++) acc[i][j] = (f32x4){0.f, 0.f, 0.f, 0.f};

  // staging: thread t -> LDS row t>>2, chunk t&3 (DMA dest is linear: t*16B).
  // global source chunk pre-swizzled so read-side XOR matches (rule #21).
  const int srow = tid >> 2;                       // 0..63
  const int schunk = (tid & 3) ^ ((tid >> 3) & 3); // = (t&3) ^ ((srow>>1)&3)
  const ushort* Ag = A + (size_t)(bm * 128 + srow) * K + schunk * 8;
  const ushort* Bg = B + (size_t)(bn * 128 + srow) * K + schunk * 8;
  ushort* Asl = As + tid * 8;   // 16B per thread, linear
  ushort* Bsl = Bs + tid * 8;
  const size_t rowstep = (size_t)64 * K;

  // fragment read offsets (ushort units): row r = wm*64+i*16+frow, 32/row
  const int frow = lane & 15;
  const int rchunk = (lane >> 4) ^ ((frow >> 1) & 3);
  int aoff[4], boff[4];
#pragma unroll
  for (int i = 0; i < 4; i++) {
    aoff[i] = (wm * 64 + i * 16 + frow) * 32 + rchunk * 8;
    boff[i] = (wn * 64 + i * 16 + frow) * 32 + rchunk * 8;
  }

  for (int k0 = 0; k0 < K; k0 += 32) {
    __syncthreads();                 // prev iter's ds_reads done
    gload16(Ag + k0, Asl);
    gload16(Ag + rowstep + k0, Asl + 2048);
    gload16(Bg + k0, Bsl);
    gload16(Bg + rowstep + k0, Bsl + 2048);
    __syncthreads();                 // drains vmcnt -> LDS ready

    short8 af[4], bfr[4];
#pragma unroll
    for (int i = 0; i < 4; i++) af[i]  = *(const short8*)&As[aoff[i]];
#pragma unroll
    for (int j = 0; j < 4; j++) bfr[j] = *(const short8*)&Bs[boff[j]];
#pragma unroll
    for (int i = 0; i < 4; i++)
#pragma unroll
      for (int j = 0; j < 4; j++)
        acc[i][j] = __builtin_amdgcn_mfma_f32_16x16x32_bf16(af[i], bfr[j], acc[i][j], 0, 0, 0);
  }

  // C/D mapping (m89): col = lane&15, row = (lane>>4)*4 + reg
  const int crow0 = bm * 128 + wm * 64;
  const int ccol0 = bn * 128 + wn * 64;
#pragma unroll
  for (int i = 0; i < 4; i++)
#pragma unroll
    for (int j = 0; j < 4; j++) {
      int col = ccol0 + j * 16 + (lane & 15);
      int rb = crow0 + i * 16 + ((lane >> 4) << 2);
#pragma unroll
      for (int r = 0; r < 4; r++)
        C[(size_t)(rb + r) * N + col] = f32_to_bf16(acc[i][j][r]);
    }
}

// ---------------- fused: LN(4H) + add input + LSTM gates + LN(H) + out -----
// One block (256 threads) per row. Each thread owns 4 columns j0..j0+3 of
// EVERY gate (j, H+j, 2H+j, 3H+j) -> no LDS transpose; LN stats are
// position-independent so the reductions don't care which elements a
// thread holds. LDS = 16 floats.
__global__ __launch_bounds__(256) void lstm_ln_kernel(
    const ushort* __restrict__ gates_pre,  // [B][4H] bf16
    const float* __restrict__ input,       // [B][4H]
    const float* __restrict__ cx,          // [B][H]
    const float* __restrict__ gamma_h, const float* __restrict__ beta_h,
    const float* __restrict__ gamma_c, const float* __restrict__ beta_c,
    float* __restrict__ hy, float* __restrict__ cy, int H) {
  const int FH = 4 * H;
  const int row = blockIdx.x;
  const int t = threadIdx.x;
  const int lane = t & 63, wv = t >> 6;
  const int j0 = t * 4;
  __shared__ float redA[8], redB[8];

  const ushort* gp = gates_pre + (size_t)row * FH;

  // load 4 bf16 per gate
  float xg[4][4];
  {
#pragma unroll
    for (int g = 0; g < 4; g++) {
      ushort4 u = *(const ushort4*)(gp + g * H + j0);
      xg[g][0] = bf16_to_f32(u.x); xg[g][1] = bf16_to_f32(u.y);
      xg[g][2] = bf16_to_f32(u.z); xg[g][3] = bf16_to_f32(u.w);
    }
  }

  float s1 = 0.f, s2 = 0.f;
#pragma unroll
  for (int g = 0; g < 4; g++)
#pragma unroll
    for (int q = 0; q < 4; q++) { s1 += xg[g][q]; s2 += xg[g][q] * xg[g][q]; }
  {
    float a = s1, b = s2;
#pragma unroll
    for (int off = 32; off > 0; off >>= 1) {
      a += __shfl_down(a, off, 64);
      b += __shfl_down(b, off, 64);
    }
    if (lane == 0) { redA[wv] = a; redA[4 + wv] = b; }
  }
  __syncthreads();
  const float inv_fh = 1.0f / (float)FH;
  const float mu  = (redA[0] + redA[1] + redA[2] + redA[3]) * inv_fh;
  const float m2  = (redA[4] + redA[5] + redA[6] + redA[7]) * inv_fh;
  const float rstd = rsqrtf(m2 - mu * mu + LN_EPS);

  const float* ip = input + (size_t)row * FH;
  float a_g[4][4];
#pragma unroll
  for (int g = 0; g < 4; g++) {
    float4 iv = *(const float4*)(ip + g * H + j0);
    float4 gv = *(const float4*)(gamma_h + g * H + j0);
    float4 bv = *(const float4*)(beta_h + g * H + j0);
    a_g[g][0] = (xg[g][0] - mu) * rstd * gv.x + bv.x + iv.x;
    a_g[g][1] = (xg[g][1] - mu) * rstd * gv.y + bv.y + iv.y;
    a_g[g][2] = (xg[g][2] - mu) * rstd * gv.z + bv.z + iv.z;
    a_g[g][3] = (xg[g][3] - mu) * rstd * gv.w + bv.w + iv.w;
  }

  float4 cxv = *(const float4*)(cx + (size_t)row * H + j0);
  const float* cxa = (const float*)&cxv;
  float cell[4], og[4];
  float s3 = 0.f, s4 = 0.f;
#pragma unroll
  for (int q = 0; q < 4; q++) {
    float in_s = sigmoid_f(a_g[0][q]);
    float fg_s = sigmoid_f(a_g[1][q]);
    float cg_t = tanh_f(a_g[2][q]);
    og[q] = sigmoid_f(a_g[3][q]);
    float cl = fg_s * cxa[q] + in_s * cg_t;
    cell[q] = cl;
    s3 += cl; s4 += cl * cl;
  }
  {
    float a = s3, b = s4;
#pragma unroll
    for (int off = 32; off > 0; off >>= 1) {
      a += __shfl_down(a, off, 64);
      b += __shfl_down(b, off, 64);
    }
    if (lane == 0) { redB[wv] = a; redB[4 + wv] = b; }
  }
  __syncthreads();
  const float inv_h = 1.0f / (float)H;
  const float mu2   = (redB[0] + redB[1] + redB[2] + redB[3]) * inv_h;
  const float m22   = (redB[4] + redB[5] + redB[6] + redB[7]) * inv_h;
  const float rstd2 = rsqrtf(m22 - mu2 * mu2 + LN_EPS);

  float4 gc = *(const float4*)(gamma_c + j0);
  float4 bc = *(const float4*)(beta_c + j0);
  const float* gca = (const float*)&gc;
  const float* bca = (const float*)&bc;
  float4 cyo, hyo;
  float* cyp = (float*)&cyo; float* hyp = (float*)&hyo;
#pragma unroll
  for (int q = 0; q < 4; q++) {
    float cyv = (cell[q] - mu2) * rstd2 * gca[q] + bca[q];
    cyp[q] = cyv;
    hyp[q] = og[q] * tanh_f(cyv);
  }
  *(float4*)(cy + (size_t)row * H + j0) = cyo;
  *(float4*)(hy + (size_t)row * H + j0) = hyo;
}

extern "C" void kernel_launch(void* const* d_in, const int* in_sizes, int n_in,
                              void* d_out, int out_size, void* d_ws, size_t ws_size,
                              hipStream_t stream) {
  (void)n_in; (void)out_size; (void)ws_size;
  const float* input   = (const float*)d_in[0];
  const float* hx      = (const float*)d_in[1];
  const float* cx      = (const float*)d_in[2];
  const float* w       = (const float*)d_in[3];
  const float* gamma_h = (const float*)d_in[4];
  const float* beta_h  = (const float*)d_in[5];
  const float* gamma_c = (const float*)d_in[6];
  const float* beta_c  = (const float*)d_in[7];

  const int H  = in_sizes[6];       // 1024
  const int B  = in_sizes[1] / H;   // 8192
  const int FH = 4 * H;             // 4096
  const int K  = H;

  ushort* hx_bf = (ushort*)d_ws;                       // B*K bf16
  ushort* w_bf  = hx_bf + (size_t)B * K;               // FH*K bf16
  ushort* gates = w_bf + (size_t)FH * K;               // B*FH bf16

  float* hy = (float*)d_out;
  float* cy = hy + (size_t)B * H;

  cast2_f32_bf16<<<2048, 256, 0, stream>>>(hx, hx_bf, (B * K) / 4,
                                           w, w_bf, (FH * K) / 4);

  dim3 grid(FH / 128, B / 128);   // (32, 64)
  gemm_bt<<<grid, 256, 0, stream>>>(hx_bf, w_bf, gates, B, FH, K);

  lstm_ln_kernel<<<B, 256, 0, stream>>>(gates, input, cx, gamma_h, beta_h,
                                        gamma_c, beta_c, hy, cy, H);
}

// Round 3
// 350.753 us; speedup vs baseline: 1.0904x; 1.0434x over previous
//
#include <hip/hip_runtime.h>
#include <hip/hip_bf16.h>

typedef __attribute__((ext_vector_type(8))) short short8;
typedef __attribute__((ext_vector_type(4))) float f32x4;

#define LN_EPS 1e-5f

__device__ __forceinline__ ushort f32_to_bf16(float f) {
  union { float f; unsigned u; } v; v.f = f;
  unsigned u = v.u;
  u += 0x7FFFu + ((u >> 16) & 1u);   // RNE
  return (ushort)(u >> 16);
}
__device__ __forceinline__ float bf16_to_f32(ushort h) {
  union { unsigned u; float f; } v; v.u = ((unsigned)h) << 16; return v.f;
}
__device__ __forceinline__ float sigmoid_f(float x) {
  return 1.0f / (1.0f + __expf(-x));
}
__device__ __forceinline__ float tanh_f(float x) {
  return 2.0f / (1.0f + __expf(-2.0f * x)) - 1.0f;
}

// async global->LDS, 16B per lane (global_load_lds_dwordx4)
__device__ __forceinline__ void gload16(const ushort* g, ushort* l) {
  __builtin_amdgcn_global_load_lds(
      (const __attribute__((address_space(1))) unsigned int*)g,
      (__attribute__((address_space(3))) unsigned int*)l, 16, 0, 0);
}

// ---------------- fused cast f32 -> bf16 for two buffers ------------------
__global__ __launch_bounds__(256) void cast2_f32_bf16(
    const float* __restrict__ a, ushort* __restrict__ oa, int na4,
    const float* __restrict__ b, ushort* __restrict__ ob, int nb4) {
  int i = blockIdx.x * 256 + threadIdx.x;
  int stride = gridDim.x * 256;
  for (; i < na4 + nb4; i += stride) {
    const float* src = (i < na4) ? a : b;
    ushort* dst = (i < na4) ? oa : ob;
    int k = (i < na4) ? i : i - na4;
    float4 v = ((const float4*)src)[k];
    ushort4 o;
    o.x = f32_to_bf16(v.x); o.y = f32_to_bf16(v.y);
    o.z = f32_to_bf16(v.z); o.w = f32_to_bf16(v.w);
    ((ushort4*)dst)[k] = o;
  }
}

// ---------------- NT bf16 GEMM, 256x256 tile, BK=64, 8 waves (2Mx4N) ------
// 4-phase K-loop (T3 shape): per phase {ds_read frags; barrier; lgkmcnt(0);
// setprio(1); 16 MFMA; setprio(0); barrier}. Next K-tile's 8 global_load_lds
// issued at phase 1 into the other buffer (issue-early); vmcnt(0) only at
// tile end (~3 phases of MFMA cover the latency). LDS 128 KB, double-buffered.
// XOR swizzle: physical chunk = logical ^ (row&7), both sides (rule #21).
#define DS_A(QM)                                                            \
  _Pragma("unroll") for (int ks = 0; ks < 2; ks++)                          \
  _Pragma("unroll") for (int m = 0; m < 4; m++)                             \
    af[ks][m] = *(const short8*)&Acur[aoff[ks] + (QM) * 4096 + m * 1024];
#define DS_B(QN)                                                            \
  _Pragma("unroll") for (int ks = 0; ks < 2; ks++)                          \
  _Pragma("unroll") for (int n = 0; n < 2; n++)                             \
    bf_[ks][n] = *(const short8*)&Bcur[boff[ks] + (QN) * 2048 + n * 1024];
#define MFMAS(QM, QN)                                                       \
  _Pragma("unroll") for (int ks = 0; ks < 2; ks++)                          \
  _Pragma("unroll") for (int m = 0; m < 4; m++)                             \
  _Pragma("unroll") for (int n = 0; n < 2; n++)                             \
    acc[(QM) * 4 + m][(QN) * 2 + n] = __builtin_amdgcn_mfma_f32_16x16x32_bf16( \
        af[ks][m], bf_[ks][n], acc[(QM) * 4 + m][(QN) * 2 + n], 0, 0, 0);
#define PHASE_SYNC_PRE()                                                    \
  __builtin_amdgcn_s_barrier();                                             \
  asm volatile("s_waitcnt lgkmcnt(0)" ::: "memory");                        \
  __builtin_amdgcn_sched_barrier(0);                                        \
  __builtin_amdgcn_s_setprio(1);
#define PHASE_SYNC_POST()                                                   \
  __builtin_amdgcn_s_setprio(0);                                            \
  __builtin_amdgcn_s_barrier();

__global__ __launch_bounds__(512, 2) void gemm_bt(const ushort* __restrict__ A,
                                                  const ushort* __restrict__ B,
                                                  ushort* __restrict__ C,
                                                  int M, int N, int K) {
  __shared__ alignas(16) ushort lds[65536];  // A: [0,32768) B: [32768,65536)
  const int tid = threadIdx.x;
  const int l = tid & 63;
  const int wv = tid >> 6;
  const int wm = wv >> 2, wn = wv & 3;   // 2 x 4 wave grid

  // XCD-aware bijective swizzle (nwg % 8 == 0)
  const int nwg = gridDim.x;
  const int cpx = nwg >> 3;
  const int bid = blockIdx.x;
  const int swz = (bid & 7) * cpx + (bid >> 3);
  const int nbn = N >> 8;
  const int bm = swz / nbn;
  const int bn = swz % nbn;

  f32x4 acc[8][4];
#pragma unroll
  for (int i = 0; i < 8; i++)
#pragma unroll
    for (int j = 0; j < 4; j++) acc[i][j] = (f32x4){0.f, 0.f, 0.f, 0.f};

  // ---- staging addresses (thread-linear LDS dest, pre-swizzled source) ----
  // 16B-unit p = l2*512 + tid; row = p>>3; phys chunk = p&7;
  // logical chunk = phys ^ (row&7) = (tid&7) ^ ((tid>>3)&7)  (l2-invariant)
  const int lc = (tid & 7) ^ ((tid >> 3) & 7);
  const ushort* srcA0 = A + (size_t)(bm * 256 + (tid >> 3)) * K + lc * 8;
  const ushort* srcB0 = B + (size_t)(bn * 256 + (tid >> 3)) * K + lc * 8;
  ushort* dstA0 = lds + tid * 8;
  ushort* dstB0 = lds + 32768 + tid * 8;
#define STAGE(BUFSEL, KCOL)                                                 \
  _Pragma("unroll") for (int l2 = 0; l2 < 4; l2++) {                        \
    gload16(srcA0 + (size_t)l2 * 64 * K + (KCOL), dstA0 + (BUFSEL) * 16384 + l2 * 4096); \
    gload16(srcB0 + (size_t)l2 * 64 * K + (KCOL), dstB0 + (BUFSEL) * 16384 + l2 * 4096); \
  }

  // ---- fragment read offsets (ushort units) ----
  // row = (wave row base) + lr; row&7 == l&7 for all m/qm -> lane-const XOR
  const int lr = l & 15;
  const int lg = l >> 4;
  const int lx = l & 7;
  int aoff[2], boff[2];
#pragma unroll
  for (int ks = 0; ks < 2; ks++) {
    const int pc = ((ks << 2) | lg) ^ lx;
    aoff[ks] = (wm * 128 + lr) * 64 + pc * 8;
    boff[ks] = (wn * 64 + lr) * 64 + pc * 8;
  }

  STAGE(0, 0);
  asm volatile("s_waitcnt vmcnt(0)" ::: "memory");
  __builtin_amdgcn_s_barrier();

  const int NT = K >> 6;   // 16 K-tiles
  for (int t = 0; t < NT; ++t) {
    const ushort* Acur = lds + (t & 1) * 16384;
    const ushort* Bcur = lds + 32768 + (t & 1) * 16384;
    const int nbuf = (t & 1) ^ 1;
    short8 af[2][4], bf_[2][2];

    // phase 1: quadrant (0,0); issue next tile's loads early
    DS_A(0); DS_B(0);
    if (t < NT - 1) { STAGE(nbuf, (t + 1) * 64); }
    PHASE_SYNC_PRE();
    MFMAS(0, 0);
    PHASE_SYNC_POST();

    // phase 2: quadrant (0,1) — reuse A frags
    DS_B(1);
    PHASE_SYNC_PRE();
    MFMAS(0, 1);
    PHASE_SYNC_POST();

    // phase 3: quadrant (1,1) — reuse B frags
    DS_A(1);
    PHASE_SYNC_PRE();
    MFMAS(1, 1);
    PHASE_SYNC_POST();

    // phase 4: quadrant (1,0)
    DS_B(0);
    PHASE_SYNC_PRE();
    MFMAS(1, 0);
    __builtin_amdgcn_s_setprio(0);
    asm volatile("s_waitcnt vmcnt(0)" ::: "memory");  // next tile's DMAs landed
    __builtin_amdgcn_s_barrier();
  }

  // ---- epilogue: C/D mapping col = lane&15, row = (lane>>4)*4 + reg ----
#pragma unroll
  for (int mi = 0; mi < 8; mi++) {
    const int rowb = bm * 256 + wm * 128 + mi * 16 + lg * 4;
#pragma unroll
    for (int ni = 0; ni < 4; ni++) {
      const int col = bn * 256 + wn * 64 + ni * 16 + lr;
#pragma unroll
      for (int r = 0; r < 4; r++)
        C[(size_t)(rowb + r) * N + col] = f32_to_bf16(acc[mi][ni][r]);
    }
  }
}

// ---------------- fused: LN(4H) + add input + LSTM gates + LN(H) + out -----
__global__ __launch_bounds__(256) void lstm_ln_kernel(
    const ushort* __restrict__ gates_pre,  // [B][4H] bf16
    const float* __restrict__ input,       // [B][4H]
    const float* __restrict__ cx,          // [B][H]
    const float* __restrict__ gamma_h, const float* __restrict__ beta_h,
    const float* __restrict__ gamma_c, const float* __restrict__ beta_c,
    float* __restrict__ hy, float* __restrict__ cy, int H) {
  const int FH = 4 * H;
  const int row = blockIdx.x;
  const int t = threadIdx.x;
  const int lane = t & 63, wv = t >> 6;
  const int j0 = t * 4;
  __shared__ float redA[8], redB[8];

  const ushort* gp = gates_pre + (size_t)row * FH;

  float xg[4][4];
#pragma unroll
  for (int g = 0; g < 4; g++) {
    ushort4 u = *(const ushort4*)(gp + g * H + j0);
    xg[g][0] = bf16_to_f32(u.x); xg[g][1] = bf16_to_f32(u.y);
    xg[g][2] = bf16_to_f32(u.z); xg[g][3] = bf16_to_f32(u.w);
  }

  float s1 = 0.f, s2 = 0.f;
#pragma unroll
  for (int g = 0; g < 4; g++)
#pragma unroll
    for (int q = 0; q < 4; q++) { s1 += xg[g][q]; s2 += xg[g][q] * xg[g][q]; }
  {
    float a = s1, b = s2;
#pragma unroll
    for (int off = 32; off > 0; off >>= 1) {
      a += __shfl_down(a, off, 64);
      b += __shfl_down(b, off, 64);
    }
    if (lane == 0) { redA[wv] = a; redA[4 + wv] = b; }
  }
  __syncthreads();
  const float inv_fh = 1.0f / (float)FH;
  const float mu  = (redA[0] + redA[1] + redA[2] + redA[3]) * inv_fh;
  const float m2  = (redA[4] + redA[5] + redA[6] + redA[7]) * inv_fh;
  const float rstd = rsqrtf(m2 - mu * mu + LN_EPS);

  const float* ip = input + (size_t)row * FH;
  float a_g[4][4];
#pragma unroll
  for (int g = 0; g < 4; g++) {
    float4 iv = *(const float4*)(ip + g * H + j0);
    float4 gv = *(const float4*)(gamma_h + g * H + j0);
    float4 bv = *(const float4*)(beta_h + g * H + j0);
    a_g[g][0] = (xg[g][0] - mu) * rstd * gv.x + bv.x + iv.x;
    a_g[g][1] = (xg[g][1] - mu) * rstd * gv.y + bv.y + iv.y;
    a_g[g][2] = (xg[g][2] - mu) * rstd * gv.z + bv.z + iv.z;
    a_g[g][3] = (xg[g][3] - mu) * rstd * gv.w + bv.w + iv.w;
  }

  float4 cxv = *(const float4*)(cx + (size_t)row * H + j0);
  const float* cxa = (const float*)&cxv;
  float cell[4], og[4];
  float s3 = 0.f, s4 = 0.f;
#pragma unroll
  for (int q = 0; q < 4; q++) {
    float in_s = sigmoid_f(a_g[0][q]);
    float fg_s = sigmoid_f(a_g[1][q]);
    float cg_t = tanh_f(a_g[2][q]);
    og[q] = sigmoid_f(a_g[3][q]);
    float cl = fg_s * cxa[q] + in_s * cg_t;
    cell[q] = cl;
    s3 += cl; s4 += cl * cl;
  }
  {
    float a = s3, b = s4;
#pragma unroll
    for (int off = 32; off > 0; off >>= 1) {
      a += __shfl_down(a, off, 64);
      b += __shfl_down(b, off, 64);
    }
    if (lane == 0) { redB[wv] = a; redB[4 + wv] = b; }
  }
  __syncthreads();
  const float inv_h = 1.0f / (float)H;
  const float mu2   = (redB[0] + redB[1] + redB[2] + redB[3]) * inv_h;
  const float m22   = (redB[4] + redB[5] + redB[6] + redB[7]) * inv_h;
  const float rstd2 = rsqrtf(m22 - mu2 * mu2 + LN_EPS);

  float4 gc = *(const float4*)(gamma_c + j0);
  float4 bc = *(const float4*)(beta_c + j0);
  const float* gca = (const float*)&gc;
  const float* bca = (const float*)&bc;
  float4 cyo, hyo;
  float* cyp = (float*)&cyo; float* hyp = (float*)&hyo;
#pragma unroll
  for (int q = 0; q < 4; q++) {
    float cyv = (cell[q] - mu2) * rstd2 * gca[q] + bca[q];
    cyp[q] = cyv;
    hyp[q] = og[q] * tanh_f(cyv);
  }
  *(float4*)(cy + (size_t)row * H + j0) = cyo;
  *(float4*)(hy + (size_t)row * H + j0) = hyo;
}

extern "C" void kernel_launch(void* const* d_in, const int* in_sizes, int n_in,
                              void* d_out, int out_size, void* d_ws, size_t ws_size,
                              hipStream_t stream) {
  (void)n_in; (void)out_size; (void)ws_size;
  const float* input   = (const float*)d_in[0];
  const float* hx      = (const float*)d_in[1];
  const float* cx      = (const float*)d_in[2];
  const float* w       = (const float*)d_in[3];
  const float* gamma_h = (const float*)d_in[4];
  const float* beta_h  = (const float*)d_in[5];
  const float* gamma_c = (const float*)d_in[6];
  const float* beta_c  = (const float*)d_in[7];

  const int H  = in_sizes[6];       // 1024
  const int B  = in_sizes[1] / H;   // 8192
  const int FH = 4 * H;             // 4096
  const int K  = H;

  ushort* hx_bf = (ushort*)d_ws;                       // B*K bf16
  ushort* w_bf  = hx_bf + (size_t)B * K;               // FH*K bf16
  ushort* gates = w_bf + (size_t)FH * K;               // B*FH bf16

  float* hy = (float*)d_out;
  float* cy = hy + (size_t)B * H;

  cast2_f32_bf16<<<2048, 256, 0, stream>>>(hx, hx_bf, (B * K) / 4,
                                           w, w_bf, (FH * K) / 4);

  const int nblocks = (B / 256) * (FH / 256);   // 32*16 = 512
  gemm_bt<<<nblocks, 512, 0, stream>>>(hx_bf, w_bf, gates, B, FH, K);

  lstm_ln_kernel<<<B, 256, 0, stream>>>(gates, input, cx, gamma_h, beta_h,
                                        gamma_c, beta_c, hy, cy, H);
}

// Round 5
// 344.431 us; speedup vs baseline: 1.1104x; 1.0184x over previous
//
#include <hip/hip_runtime.h>
#include <hip/hip_bf16.h>

typedef __attribute__((ext_vector_type(8))) short short8;
typedef __attribute__((ext_vector_type(4))) float f32x4;

#define LN_EPS 1e-5f

__device__ __forceinline__ ushort f32_to_bf16(float f) {
  union { float f; unsigned u; } v; v.f = f;
  unsigned u = v.u;
  u += 0x7FFFu + ((u >> 16) & 1u);   // RNE
  return (ushort)(u >> 16);
}
__device__ __forceinline__ float bf16_to_f32(ushort h) {
  union { unsigned u; float f; } v; v.u = ((unsigned)h) << 16; return v.f;
}
__device__ __forceinline__ float sigmoid_f(float x) {
  return 1.0f / (1.0f + __expf(-x));
}
__device__ __forceinline__ float tanh_f(float x) {
  return 2.0f / (1.0f + __expf(-2.0f * x)) - 1.0f;
}

// async global->LDS, 16B per lane (global_load_lds_dwordx4)
__device__ __forceinline__ void gload16(const ushort* g, ushort* l) {
  __builtin_amdgcn_global_load_lds(
      (const __attribute__((address_space(1))) unsigned int*)g,
      (__attribute__((address_space(3))) unsigned int*)l, 16, 0, 0);
}

// ---------------- fused cast f32 -> bf16 for two buffers ------------------
__global__ __launch_bounds__(256) void cast2_f32_bf16(
    const float* __restrict__ a, ushort* __restrict__ oa, int na4,
    const float* __restrict__ b, ushort* __restrict__ ob, int nb4) {
  int i = blockIdx.x * 256 + threadIdx.x;
  int stride = gridDim.x * 256;
  for (; i < na4 + nb4; i += stride) {
    const float* src = (i < na4) ? a : b;
    ushort* dst = (i < na4) ? oa : ob;
    int k = (i < na4) ? i : i - na4;
    float4 v = ((const float4*)src)[k];
    ushort4 o;
    o.x = f32_to_bf16(v.x); o.y = f32_to_bf16(v.y);
    o.z = f32_to_bf16(v.z); o.w = f32_to_bf16(v.w);
    ((ushort4*)dst)[k] = o;
  }
}

// ---------------- NT bf16 GEMM, 256x256 tile, BK=64, 8 waves (2Mx4N) ------
// T3+T4 counted-vmcnt pipeline, RACE-FIXED: phase p's ds_read is issued
// BEFORE p's barrier, so each half-tile must be vmcnt-confirmed at the
// SYNC_PRE of the phase BEFORE its consuming ds_read (one barrier pair then
// separates DMA-confirm from read). Consumption: p1:{A_lo,B_lo} p2:B_hi
// p3:A_hi p4:(re-reads B_lo). Stage order (tile t+1, during t):
// p1:A_lo p2:B_lo p3:B_hi p4:A_hi. Solved waits: p1 vmcnt(4) [confirms
// B_hi(t)], p2 vmcnt(4) [A_hi(t)], p3 vmcnt(6) [no-op], p4 vmcnt(4)
// [A_lo,B_lo(t+1)]. Never 0 in main loop; tail 2/0/0.
// XOR swizzle: phys chunk = logical ^ (region_row & 7), both sides.
#define DS_A(QM)                                                            \
  _Pragma("unroll") for (int ks = 0; ks < 2; ks++)                          \
  _Pragma("unroll") for (int m = 0; m < 4; m++)                             \
    af[ks][m] = *(const short8*)&lds[bufo + (QM) * 8192 + aoffs[ks] + m * 1024];
#define DS_B(QN)                                                            \
  _Pragma("unroll") for (int ks = 0; ks < 2; ks++)                          \
  _Pragma("unroll") for (int n = 0; n < 2; n++)                             \
    bf_[ks][n] = *(const short8*)&lds[32768 + bufo + (QN) * 8192 + boffs[ks] + n * 1024];
#define MFMAS(QM, QN)                                                       \
  _Pragma("unroll") for (int ks = 0; ks < 2; ks++)                          \
  _Pragma("unroll") for (int m = 0; m < 4; m++)                             \
  _Pragma("unroll") for (int n = 0; n < 2; n++)                             \
    acc[QM][m][QN][n] = __builtin_amdgcn_mfma_f32_16x16x32_bf16(            \
        af[ks][m], bf_[ks][n], acc[QM][m][QN][n], 0, 0, 0);
// A half h of the K-tile at column kc, into dbuf slot bsel
#define STAGE_A(bsel, h, kc)                                                \
  { gload16(A + (size_t)(bm * 256 + (h) * 64 + arow0) * K + (kc) + lc8,     \
            lds + (bsel) * 16384 + (h) * 8192 + tid * 8);                   \
    gload16(A + (size_t)(bm * 256 + (h) * 64 + 128 + arow0) * K + (kc) + lc8, \
            lds + (bsel) * 16384 + (h) * 8192 + 4096 + tid * 8); }
#define STAGE_B(bsel, h, kc)                                                \
  { gload16(B + (size_t)(bn * 256 + (h) * 32 + brow0) * K + (kc) + lc8,     \
            lds + 32768 + (bsel) * 16384 + (h) * 8192 + tid * 8);           \
    gload16(B + (size_t)(bn * 256 + (h) * 32 + brow0 + 128) * K + (kc) + lc8, \
            lds + 32768 + (bsel) * 16384 + (h) * 8192 + 4096 + tid * 8); }
#define SYNC_PRE(VNSTR)                                                     \
  asm volatile("s_waitcnt vmcnt(" VNSTR ")" ::: "memory");                  \
  __builtin_amdgcn_s_barrier();                                             \
  asm volatile("s_waitcnt lgkmcnt(0)" ::: "memory");                        \
  __builtin_amdgcn_sched_barrier(0);                                        \
  __builtin_amdgcn_s_setprio(1);
#define SYNC_POST()                                                         \
  __builtin_amdgcn_s_setprio(0);                                            \
  __builtin_amdgcn_s_barrier();

__global__ __launch_bounds__(512, 2) void gemm_bt(const ushort* __restrict__ A,
                                                  const ushort* __restrict__ B,
                                                  ushort* __restrict__ C,
                                                  int M, int N, int K) {
  __shared__ alignas(16) ushort lds[65536];  // A: [0,32768) B: [32768,65536)
  const int tid = threadIdx.x;
  const int l = tid & 63;
  const int wv = tid >> 6;
  const int wm = wv >> 2, wn = wv & 3;   // 2 x 4 wave grid

  // XCD-aware bijective swizzle (nwg % 8 == 0)
  const int nwg = gridDim.x;
  const int cpx = nwg >> 3;
  const int bid = blockIdx.x;
  const int swz = (bid & 7) * cpx + (bid >> 3);
  const int nbn = N >> 8;
  const int bm = swz / nbn;
  const int bn = swz % nbn;

  f32x4 acc[2][4][2][2];
#pragma unroll
  for (int qm = 0; qm < 2; qm++)
#pragma unroll
    for (int m = 0; m < 4; m++)
#pragma unroll
      for (int qn = 0; qn < 2; qn++)
#pragma unroll
        for (int n = 0; n < 2; n++) acc[qm][m][qn][n] = (f32x4){0.f, 0.f, 0.f, 0.f};

  // ---- staging addresses ----
  const int arow0 = tid >> 3;   // 0..63 (second gload adds +128)
  const int q8 = tid >> 3;
  const int brow0 = (q8 & 31) + ((q8 >> 5) << 6);   // B row for first gload
  const int lc8 = ((tid & 7) ^ ((tid >> 3) & 7)) * 8;  // pre-swizzled chunk

  // ---- fragment read offsets (ushort units within a half-region) ----
  const int lr = l & 15;
  const int lg = (l >> 4) & 3;
  const int lx = l & 7;
  int aoffs[2], boffs[2];
#pragma unroll
  for (int ks = 0; ks < 2; ks++) {
    const int pc = ((ks << 2) | lg) ^ lx;
    aoffs[ks] = (wm * 64 + lr) * 64 + pc * 8;
    boffs[ks] = (wn * 32 + lr) * 64 + pc * 8;
  }

  // ---- prologue: stage all of tile 0, full drain once ----
  STAGE_A(0, 0, 0);
  STAGE_B(0, 0, 0);
  STAGE_B(0, 1, 0);
  STAGE_A(0, 1, 0);
  asm volatile("s_waitcnt vmcnt(0)" ::: "memory");
  __builtin_amdgcn_s_barrier();

  const int NT = K >> 6;   // 16 K-tiles
  for (int t = 0; t < NT - 1; ++t) {
    const int bufo = (t & 1) * 16384;
    const int nb = (t + 1) & 1;
    const int kc = (t + 1) << 6;
    short8 af[2][4], bf_[2][2];

    // p1: Q(0,0); stage A_lo(t+1); confirm B_hi(t) for p2
    DS_A(0); DS_B(0);
    STAGE_A(nb, 0, kc);
    SYNC_PRE("4");
    MFMAS(0, 0);
    SYNC_POST();

    // p2: Q(0,1); stage B_lo(t+1); confirm A_hi(t) for p3
    DS_B(1);
    STAGE_B(nb, 0, kc);
    SYNC_PRE("4");
    MFMAS(0, 1);
    SYNC_POST();

    // p3: Q(1,1); stage B_hi(t+1); nothing to confirm
    DS_A(1);
    STAGE_B(nb, 1, kc);
    SYNC_PRE("6");
    MFMAS(1, 1);
    SYNC_POST();

    // p4: Q(1,0); stage A_hi(t+1); confirm A_lo+B_lo(t+1) for next p1
    DS_B(0);
    STAGE_A(nb, 1, kc);
    SYNC_PRE("4");
    MFMAS(1, 0);
    SYNC_POST();
  }

  // ---- tail tile (no staging): entering with 4 outstanding {B_hi,A_hi} ---
  {
    const int t = NT - 1;
    const int bufo = (t & 1) * 16384;
    short8 af[2][4], bf_[2][2];

    DS_A(0); DS_B(0);
    SYNC_PRE("2");     // confirm B_hi(tail) for p2
    MFMAS(0, 0);
    SYNC_POST();

    DS_B(1);
    SYNC_PRE("0");     // confirm A_hi(tail) for p3
    MFMAS(0, 1);
    SYNC_POST();

    DS_A(1);
    SYNC_PRE("0");
    MFMAS(1, 1);
    SYNC_POST();

    DS_B(0);
    __builtin_amdgcn_s_barrier();
    asm volatile("s_waitcnt lgkmcnt(0)" ::: "memory");
    __builtin_amdgcn_sched_barrier(0);
    MFMAS(1, 0);
  }

  // ---- epilogue: C/D mapping col = lane&15, row = (lane>>4)*4 + reg ----
#pragma unroll
  for (int qm = 0; qm < 2; qm++)
#pragma unroll
    for (int m = 0; m < 4; m++) {
      const int rowb = bm * 256 + wm * 128 + qm * 64 + m * 16 + lg * 4;
#pragma unroll
      for (int qn = 0; qn < 2; qn++)
#pragma unroll
        for (int n = 0; n < 2; n++) {
          const int col = bn * 256 + wn * 64 + qn * 32 + n * 16 + lr;
#pragma unroll
          for (int r = 0; r < 4; r++)
            C[(size_t)(rowb + r) * N + col] = f32_to_bf16(acc[qm][m][qn][n][r]);
        }
    }
}

// ---------------- fused: LN(4H) + add input + LSTM gates + LN(H) + out -----
__global__ __launch_bounds__(256) void lstm_ln_kernel(
    const ushort* __restrict__ gates_pre,  // [B][4H] bf16
    const float* __restrict__ input,       // [B][4H]
    const float* __restrict__ cx,          // [B][H]
    const float* __restrict__ gamma_h, const float* __restrict__ beta_h,
    const float* __restrict__ gamma_c, const float* __restrict__ beta_c,
    float* __restrict__ hy, float* __restrict__ cy, int H) {
  const int FH = 4 * H;
  const int row = blockIdx.x;
  const int t = threadIdx.x;
  const int lane = t & 63, wv = t >> 6;
  const int j0 = t * 4;
  __shared__ float redA[8], redB[8];

  const ushort* gp = gates_pre + (size_t)row * FH;

  float xg[4][4];
#pragma unroll
  for (int g = 0; g < 4; g++) {
    ushort4 u = *(const ushort4*)(gp + g * H + j0);
    xg[g][0] = bf16_to_f32(u.x); xg[g][1] = bf16_to_f32(u.y);
    xg[g][2] = bf16_to_f32(u.z); xg[g][3] = bf16_to_f32(u.w);
  }

  float s1 = 0.f, s2 = 0.f;
#pragma unroll
  for (int g = 0; g < 4; g++)
#pragma unroll
    for (int q = 0; q < 4; q++) { s1 += xg[g][q]; s2 += xg[g][q] * xg[g][q]; }
  {
    float a = s1, b = s2;
#pragma unroll
    for (int off = 32; off > 0; off >>= 1) {
      a += __shfl_down(a, off, 64);
      b += __shfl_down(b, off, 64);
    }
    if (lane == 0) { redA[wv] = a; redA[4 + wv] = b; }
  }
  __syncthreads();
  const float inv_fh = 1.0f / (float)FH;
  const float mu  = (redA[0] + redA[1] + redA[2] + redA[3]) * inv_fh;
  const float m2  = (redA[4] + redA[5] + redA[6] + redA[7]) * inv_fh;
  const float rstd = rsqrtf(m2 - mu * mu + LN_EPS);

  const float* ip = input + (size_t)row * FH;
  float a_g[4][4];
#pragma unroll
  for (int g = 0; g < 4; g++) {
    float4 iv = *(const float4*)(ip + g * H + j0);
    float4 gv = *(const float4*)(gamma_h + g * H + j0);
    float4 bv = *(const float4*)(beta_h + g * H + j0);
    a_g[g][0] = (xg[g][0] - mu) * rstd * gv.x + bv.x + iv.x;
    a_g[g][1] = (xg[g][1] - mu) * rstd * gv.y + bv.y + iv.y;
    a_g[g][2] = (xg[g][2] - mu) * rstd * gv.z + bv.z + iv.z;
    a_g[g][3] = (xg[g][3] - mu) * rstd * gv.w + bv.w + iv.w;
  }

  float4 cxv = *(const float4*)(cx + (size_t)row * H + j0);
  const float* cxa = (const float*)&cxv;
  float cell[4], og[4];
  float s3 = 0.f, s4 = 0.f;
#pragma unroll
  for (int q = 0; q < 4; q++) {
    float in_s = sigmoid_f(a_g[0][q]);
    float fg_s = sigmoid_f(a_g[1][q]);
    float cg_t = tanh_f(a_g[2][q]);
    og[q] = sigmoid_f(a_g[3][q]);
    float cl = fg_s * cxa[q] + in_s * cg_t;
    cell[q] = cl;
    s3 += cl; s4 += cl * cl;
  }
  {
    float a = s3, b = s4;
#pragma unroll
    for (int off = 32; off > 0; off >>= 1) {
      a += __shfl_down(a, off, 64);
      b += __shfl_down(b, off, 64);
    }
    if (lane == 0) { redB[wv] = a; redB[4 + wv] = b; }
  }
  __syncthreads();
  const float inv_h = 1.0f / (float)H;
  const float mu2   = (redB[0] + redB[1] + redB[2] + redB[3]) * inv_h;
  const float m22   = (redB[4] + redB[5] + redB[6] + redB[7]) * inv_h;
  const float rstd2 = rsqrtf(m22 - mu2 * mu2 + LN_EPS);

  float4 gc = *(const float4*)(gamma_c + j0);
  float4 bc = *(const float4*)(beta_c + j0);
  const float* gca = (const float*)&gc;
  const float* bca = (const float*)&bc;
  float4 cyo, hyo;
  float* cyp = (float*)&cyo; float* hyp = (float*)&hyo;
#pragma unroll
  for (int q = 0; q < 4; q++) {
    float cyv = (cell[q] - mu2) * rstd2 * gca[q] + bca[q];
    cyp[q] = cyv;
    hyp[q] = og[q] * tanh_f(cyv);
  }
  *(float4*)(cy + (size_t)row * H + j0) = cyo;
  *(float4*)(hy + (size_t)row * H + j0) = hyo;
}

extern "C" void kernel_launch(void* const* d_in, const int* in_sizes, int n_in,
                              void* d_out, int out_size, void* d_ws, size_t ws_size,
                              hipStream_t stream) {
  (void)n_in; (void)out_size; (void)ws_size;
  const float* input   = (const float*)d_in[0];
  const float* hx      = (const float*)d_in[1];
  const float* cx      = (const float*)d_in[2];
  const float* w       = (const float*)d_in[3];
  const float* gamma_h = (const float*)d_in[4];
  const float* beta_h  = (const float*)d_in[5];
  const float* gamma_c = (const float*)d_in[6];
  const float* beta_c  = (const float*)d_in[7];

  const int H  = in_sizes[6];       // 1024
  const int B  = in_sizes[1] / H;   // 8192
  const int FH = 4 * H;             // 4096
  const int K  = H;

  ushort* hx_bf = (ushort*)d_ws;                       // B*K bf16
  ushort* w_bf  = hx_bf + (size_t)B * K;               // FH*K bf16
  ushort* gates = w_bf + (size_t)FH * K;               // B*FH bf16

  float* hy = (float*)d_out;
  float* cy = hy + (size_t)B * H;

  cast2_f32_bf16<<<2048, 256, 0, stream>>>(hx, hx_bf, (B * K) / 4,
                                           w, w_bf, (FH * K) / 4);

  const int nblocks = (B / 256) * (FH / 256);   // 32*16 = 512
  gemm_bt<<<nblocks, 512, 0, stream>>>(hx_bf, w_bf, gates, B, FH, K);

  lstm_ln_kernel<<<B, 256, 0, stream>>>(gates, input, cx, gamma_h, beta_h,
                                        gamma_c, beta_c, hy, cy, H);
}